// Round 2
// baseline (7528.275 us; speedup 1.0000x reference)
//
#include <hip/hip_runtime.h>
#include <math.h>

#define TT_ 128
#define DD 64
#define HH 256
#define BB 16      // batch rows per block (MFMA M-tile)
#define NBLK 64    // 1024/16
#define NTHR 512   // 8 waves

// LDS strides (f32 elements). 260*4B = 1040B = 65*16B (odd) -> quarter-wave
// b128 reads of rows 0..7 hit distinct bank-quads (2-way aliasing = free).
#define SA 260
#define SX 68      // 68*4 = 272B = 17*16B (odd)
#define SG 516     // 516*4 = 2064B = 129*16B (odd)

typedef short bf16x8 __attribute__((ext_vector_type(8)));
typedef float f32x4 __attribute__((ext_vector_type(4)));
typedef unsigned int uint;
typedef unsigned short ushort;
typedef uint u32x4 __attribute__((ext_vector_type(4)));

// ---- fragment-linear packed weights (bf16 hi/lo pairs), written by prep ----
// layout [tile][koct][term][lane*8+j] ; frag elem = W[t*16 + l%16][o*32 + (l/16)*8 + j]
__device__ ushort g_W1p[16 * 8 * 2 * 512];    // W1  (256x256)
__device__ ushort g_W2p[16 * 8 * 2 * 512];    // W2  (256x256)
__device__ ushort g_Wrzp[32 * 10 * 2 * 512];  // [Whh rows 0..511 | Wih rows 0..511] K=256(+64)
__device__ ushort g_Whnp[16 * 8 * 2 * 512];   // Whh rows 512..767
__device__ ushort g_Winp[16 * 2 * 512];       // Wih rows 512..767 (hi only)

__device__ __forceinline__ ushort bf16_rne(float f) {
  uint u = __builtin_bit_cast(uint, f);
  return (ushort)((u + 0x7fffu + ((u >> 16) & 1u)) >> 16);
}
__device__ __forceinline__ float bf16_f32(ushort h) {
  uint u = ((uint)h) << 16;
  return __builtin_bit_cast(float, u);
}

__global__ __launch_bounds__(256) void prep(
    const float* __restrict__ W1, const float* __restrict__ W2,
    const float* __restrict__ Wih, const float* __restrict__ Whh)
{
  const int s = blockIdx.x * 256 + threadIdx.x;
  const int S1 = 16 * 8 * 512;        // 65536   W1
  const int S2 = S1 + 16 * 8 * 512;   // 131072  W2
  const int S3 = S2 + 32 * 10 * 512;  // 294912  Wrz
  const int S4 = S3 + 16 * 8 * 512;   // 360448  Whn
  const int S5 = S4 + 16 * 2 * 512;   // 376832  Win
  if (s >= S5) return;

  if (s < S2) {  // W1 / W2
    const int r = (s < S1) ? s : s - S1;
    const int t = r / (8 * 512);
    const int o = (r / 512) & 7;
    const int pos = r & 511;
    const int l = pos >> 3, j = pos & 7;
    const int n = t * 16 + (l & 15);
    const int k = o * 32 + (l >> 4) * 8 + j;
    const float w = (s < S1) ? W1[n * HH + k] : W2[n * HH + k];
    ushort hi = bf16_rne(w);
    ushort lo = bf16_rne(w - bf16_f32(hi));
    ushort* dst = (s < S1) ? g_W1p : g_W2p;
    dst[((t * 8 + o) * 2) * 512 + pos] = hi;
    dst[((t * 8 + o) * 2 + 1) * 512 + pos] = lo;
  } else if (s < S3) {  // Wrz
    const int r = s - S2;
    const int t = r / (10 * 512);
    const int o = (r / 512) % 10;
    const int pos = r & 511;
    const int l = pos >> 3, j = pos & 7;
    const int n = t * 16 + (l & 15);  // 0..511 (gates r,z)
    float w;
    if (o < 8) w = Whh[n * HH + o * 32 + (l >> 4) * 8 + j];
    else       w = Wih[n * DD + (o - 8) * 32 + (l >> 4) * 8 + j];
    ushort hi = bf16_rne(w);
    ushort lo = bf16_rne(w - bf16_f32(hi));
    g_Wrzp[((t * 10 + o) * 2) * 512 + pos] = hi;
    g_Wrzp[((t * 10 + o) * 2 + 1) * 512 + pos] = lo;
  } else if (s < S4) {  // Whn
    const int r = s - S3;
    const int t = r / (8 * 512);
    const int o = (r / 512) & 7;
    const int pos = r & 511;
    const int l = pos >> 3, j = pos & 7;
    const int n = 512 + t * 16 + (l & 15);
    const float w = Whh[n * HH + o * 32 + (l >> 4) * 8 + j];
    ushort hi = bf16_rne(w);
    ushort lo = bf16_rne(w - bf16_f32(hi));
    g_Whnp[((t * 8 + o) * 2) * 512 + pos] = hi;
    g_Whnp[((t * 8 + o) * 2 + 1) * 512 + pos] = lo;
  } else {  // Win (hi only)
    const int r = s - S4;
    const int t = r / (2 * 512);
    const int o = (r / 512) & 1;
    const int pos = r & 511;
    const int l = pos >> 3, j = pos & 7;
    const int n = 512 + t * 16 + (l & 15);
    const float w = Wih[n * DD + o * 32 + (l >> 4) * 8 + j];
    g_Winp[(t * 2 + o) * 512 + pos] = bf16_rne(w);
  }
}

// Build A hi/lo bf16x8 fragments from 8 consecutive f32 in LDS.
// hi = truncation; lo = exact residual truncated -> AhiW + AloW ~ fp32 product.
__device__ __forceinline__ void build_frags(const float* __restrict__ ap,
                                            bf16x8& ahi, bf16x8& alo)
{
  const float4 a0 = *(const float4*)ap;
  const float4 a1 = *(const float4*)(ap + 4);
  float af[8] = {a0.x, a0.y, a0.z, a0.w, a1.x, a1.y, a1.z, a1.w};
  uint hu[4], lu[4];
#pragma unroll
  for (int jj = 0; jj < 4; ++jj) {
    const uint ue = __builtin_bit_cast(uint, af[2 * jj]);
    const uint uo = __builtin_bit_cast(uint, af[2 * jj + 1]);
    hu[jj] = (ue >> 16) | (uo & 0xffff0000u);
    const float he = __builtin_bit_cast(float, ue & 0xffff0000u);
    const float ho = __builtin_bit_cast(float, uo & 0xffff0000u);
    const uint le = __builtin_bit_cast(uint, af[2 * jj] - he);
    const uint lo = __builtin_bit_cast(uint, af[2 * jj + 1] - ho);
    lu[jj] = (le >> 16) | (lo & 0xffff0000u);
  }
  u32x4 hv = {hu[0], hu[1], hu[2], hu[3]};
  u32x4 lv = {lu[0], lu[1], lu[2], lu[3]};
  ahi = __builtin_bit_cast(bf16x8, hv);
  alo = __builtin_bit_cast(bf16x8, lv);
}

#define MFMA(A, B, C) __builtin_amdgcn_mfma_f32_16x16x32_bf16((A), (B), (C), 0, 0, 0)

// 2 N-tiles (t0, t0+1), K=256, 3-term split accumulation.
__device__ __forceinline__ void mm2t3(const float* __restrict__ src, int stride,
                                      const ushort* __restrict__ pack, int t0,
                                      int lane, f32x4& acc0, f32x4& acc1)
{
  const int l15 = lane & 15, lq = lane >> 4;
  const ushort* pb = pack + lane * 8;
#pragma unroll
  for (int o = 0; o < 8; ++o) {
    bf16x8 ahi, alo;
    build_frags(src + l15 * stride + o * 32 + lq * 8, ahi, alo);
    const ushort* p0 = pb + ((t0 * 8 + o) * 2) * 512;
    const ushort* p1 = pb + (((t0 + 1) * 8 + o) * 2) * 512;
    const bf16x8 w0h = *(const bf16x8*)p0;
    const bf16x8 w0l = *(const bf16x8*)(p0 + 512);
    const bf16x8 w1h = *(const bf16x8*)p1;
    const bf16x8 w1l = *(const bf16x8*)(p1 + 512);
    acc0 = MFMA(ahi, w0h, acc0);
    acc1 = MFMA(ahi, w1h, acc1);
    acc0 = MFMA(alo, w0h, acc0);
    acc1 = MFMA(alo, w1h, acc1);
    acc0 = MFMA(ahi, w0l, acc0);
    acc1 = MFMA(ahi, w1l, acc1);
  }
}

// GRU r,z fused matmul: N=512 (4 tiles/wave), K = 256 (h_ode, 3-term) + 64 (x, 2-term)
__device__ __forceinline__ void mm_rz(const float* __restrict__ hsrc,
                                      const float* __restrict__ xsrc,
                                      int lane, int w, f32x4 az[4])
{
  const int l15 = lane & 15, lq = lane >> 4;
  const ushort* pb = g_Wrzp + lane * 8;
#pragma unroll
  for (int o = 0; o < 8; ++o) {
    bf16x8 ahi, alo;
    build_frags(hsrc + l15 * SA + o * 32 + lq * 8, ahi, alo);
#pragma unroll
    for (int q = 0; q < 4; ++q) {
      const int t = 4 * w + q;
      const ushort* p = pb + ((t * 10 + o) * 2) * 512;
      const bf16x8 wh = *(const bf16x8*)p;
      const bf16x8 wl = *(const bf16x8*)(p + 512);
      az[q] = MFMA(ahi, wh, az[q]);
      az[q] = MFMA(alo, wh, az[q]);
      az[q] = MFMA(ahi, wl, az[q]);
    }
  }
#pragma unroll
  for (int o = 0; o < 2; ++o) {
    bf16x8 ahi, alo;
    build_frags(xsrc + l15 * SX + o * 32 + lq * 8, ahi, alo);
#pragma unroll
    for (int q = 0; q < 4; ++q) {
      const int t = 4 * w + q;
      const ushort* p = pb + ((t * 10 + 8 + o) * 2) * 512;
      const bf16x8 wh = *(const bf16x8*)p;
      az[q] = MFMA(ahi, wh, az[q]);
      az[q] = MFMA(alo, wh, az[q]);
    }
  }
}

// GRU n-gate x-side: N=256 (2 tiles/wave), K=64, hi-only weights, 2-term
__device__ __forceinline__ void mm_in_f(const float* __restrict__ xsrc,
                                        int lane, int t0, f32x4& acc0, f32x4& acc1)
{
  const int l15 = lane & 15, lq = lane >> 4;
#pragma unroll
  for (int o = 0; o < 2; ++o) {
    bf16x8 ahi, alo;
    build_frags(xsrc + l15 * SX + o * 32 + lq * 8, ahi, alo);
    const bf16x8 w0 = *(const bf16x8*)(g_Winp + (t0 * 2 + o) * 512 + lane * 8);
    const bf16x8 w1 = *(const bf16x8*)(g_Winp + ((t0 + 1) * 2 + o) * 512 + lane * 8);
    acc0 = MFMA(ahi, w0, acc0);
    acc0 = MFMA(alo, w0, acc0);
    acc1 = MFMA(ahi, w1, acc1);
    acc1 = MFMA(alo, w1, acc1);
  }
}

__global__ __launch_bounds__(NTHR, 2) void odegru_kernel(
    const float* __restrict__ x, const float* __restrict__ times,
    const float* __restrict__ mask,
    const float* __restrict__ b1, const float* __restrict__ b2,
    const float* __restrict__ bih, const float* __restrict__ bhh,
    float* __restrict__ out)
{
  __shared__ __align__(16) float sAh[BB * SA];   // h state (f32)
  __shared__ __align__(16) float sAin[BB * SA];  // feval input / h_ode
  __shared__ __align__(16) float sU[BB * SA];    // relu intermediate
  __shared__ __align__(16) float sX[BB * SX];    // x[:, t, :]
  __shared__ __align__(16) float sGRZ[BB * SG];  // r,z pre-activations (512)
  __shared__ __align__(16) float sGHN[BB * SA];  // h-side n pre-act
  __shared__ __align__(16) float sGIN[BB * SA];  // x-side n pre-act

  const int tid = threadIdx.x;
  const int lane = tid & 63;
  const int w = tid >> 6;      // wave 0..7
  const int l15 = lane & 15;
  const int lq = lane >> 4;    // 0..3
  const int b0 = blockIdx.x * BB;

  // frag-epilogue columns + biases for this thread's 2 feval tiles
  const int c0 = (2 * w) * 16 + l15;
  const int c1 = (2 * w + 1) * 16 + l15;
  const float b1c0 = b1[c0], b1c1 = b1[c1];
  const float b2c0 = b2[c0], b2c1 = b2[c1];

  // pointwise mapping: dim pi, 8 batches starting at pb0
  const int pi = tid & 255;
  const int pb0 = (tid >> 8) * 8;
  const float brz_r = bih[pi] + bhh[pi];
  const float brz_z = bih[pi + 256] + bhh[pi + 256];
  const float bn_i = bih[pi + 512];
  const float bn_h = bhh[pi + 512];

  const f32x4 Z = {0.f, 0.f, 0.f, 0.f};

  auto feval = [&](const float* src, f32x4& kv0, f32x4& kv1) {
    f32x4 a0 = Z, a1 = Z;
    mm2t3(src, SA, g_W1p, 2 * w, lane, a0, a1);
#pragma unroll
    for (int r = 0; r < 4; ++r) {
      const int b = lq * 4 + r;
      sU[b * SA + c0] = fmaxf(a0[r] + b1c0, 0.f);
      sU[b * SA + c1] = fmaxf(a1[r] + b1c1, 0.f);
    }
    __syncthreads();
    f32x4 p0 = Z, p1 = Z;
    mm2t3(sU, SA, g_W2p, 2 * w, lane, p0, p1);
    kv0 = p0 + b2c0;
    kv1 = p1 + b2c1;
  };

  auto wAin = [&](float coef, const f32x4& v0, const f32x4& v1) {
#pragma unroll
    for (int r = 0; r < 4; ++r) {
      const int b = lq * 4 + r;
      sAin[b * SA + c0] = sAh[b * SA + c0] + coef * v0[r];
      sAin[b * SA + c1] = sAh[b * SA + c1] + coef * v1[r];
    }
  };

  for (int t = 0; t < TT_; ++t) {
    // stage x[:, t, :]
    {
      const int b = tid >> 5, d = (tid & 31) * 2;
      const float2 v = *(const float2*)&x[((size_t)(b0 + b) * TT_ + t) * DD + d];
      sX[b * SX + d] = v.x;
      sX[b * SX + d + 1] = v.y;
    }
    if (t == 0) {
#pragma unroll
      for (int q = 0; q < 8; ++q) {  // h_ode = h0-input = 0
        const int idx = tid * 8 + q;
        sAin[(idx >> 8) * SA + (idx & 255)] = 0.f;
      }
    }
    __syncthreads();

    if (t > 0) {
      const float dtv = times[t] - times[t - 1];
      f32x4 kv0, kv1, ks0, ks1;
      // k1 (reads h state)
      feval(sAh, kv0, kv1);
      ks0 = kv0; ks1 = kv1;
      wAin(0.5f * dtv, kv0, kv1);
      __syncthreads();
      // k2
      feval(sAin, kv0, kv1);
      ks0 += 2.0f * kv0; ks1 += 2.0f * kv1;
      wAin(0.5f * dtv, kv0, kv1);
      __syncthreads();
      // k3
      feval(sAin, kv0, kv1);
      ks0 += 2.0f * kv0; ks1 += 2.0f * kv1;
      wAin(dtv, kv0, kv1);
      __syncthreads();
      // k4
      feval(sAin, kv0, kv1);
      ks0 += kv0; ks1 += kv1;
      wAin(dtv * (1.0f / 6.0f), ks0, ks1);  // sAin <- h_ode
      __syncthreads();
    }

    // ---- GRU matmuls (read sAin, sX) ----
    {
      f32x4 az[4] = {Z, Z, Z, Z};
      mm_rz(sAin, sX, lane, w, az);
#pragma unroll
      for (int q = 0; q < 4; ++q)
#pragma unroll
        for (int r = 0; r < 4; ++r) {
          const int b = lq * 4 + r;
          sGRZ[b * SG + (4 * w + q) * 16 + l15] = az[q][r];
        }
      f32x4 h0 = Z, h1 = Z;
      mm2t3(sAin, SA, g_Whnp, 2 * w, lane, h0, h1);
      f32x4 i0 = Z, i1 = Z;
      mm_in_f(sX, lane, 2 * w, i0, i1);
#pragma unroll
      for (int r = 0; r < 4; ++r) {
        const int b = lq * 4 + r;
        sGHN[b * SA + c0] = h0[r];
        sGHN[b * SA + c1] = h1[r];
        sGIN[b * SA + c0] = i0[r];
        sGIN[b * SA + c1] = i1[r];
      }
    }
    __syncthreads();

    // ---- GRU pointwise ----
#pragma unroll
    for (int bb = 0; bb < 8; ++bb) {
      const int b = pb0 + bb;
      const float gr = sGRZ[b * SG + pi] + brz_r;
      const float gz = sGRZ[b * SG + pi + 256] + brz_z;
      const float hn = sGHN[b * SA + pi] + bn_h;
      const float gn = sGIN[b * SA + pi] + bn_i;
      const float hode = sAin[b * SA + pi];
      const float rg = 1.f / (1.f + __expf(-gr));
      const float zg = 1.f / (1.f + __expf(-gz));
      const float ng = 1.f - 2.f / (__expf(2.f * (gn + rg * hn)) + 1.f);
      const float hnext = (1.f - zg) * ng + zg * hode;
      const float m = mask[(size_t)(b0 + b) * TT_ + t];
      const float hnew = m * hnext + (1.f - m) * hode;
      sAh[b * SA + pi] = hnew;
      out[((size_t)(b0 + b) * TT_ + t) * HH + pi] = hnew;
    }
    __syncthreads();
  }
}

extern "C" void kernel_launch(void* const* d_in, const int* in_sizes, int n_in,
                              void* d_out, int out_size, void* d_ws, size_t ws_size,
                              hipStream_t stream) {
  (void)in_sizes; (void)n_in; (void)d_ws; (void)ws_size; (void)out_size;
  const float* x     = (const float*)d_in[0];
  const float* times = (const float*)d_in[1];
  const float* mask  = (const float*)d_in[2];
  const float* W1    = (const float*)d_in[3];
  const float* b1    = (const float*)d_in[4];
  const float* W2    = (const float*)d_in[5];
  const float* b2    = (const float*)d_in[6];
  const float* Wih   = (const float*)d_in[7];
  const float* bih   = (const float*)d_in[8];
  const float* Whh   = (const float*)d_in[9];
  const float* bhh   = (const float*)d_in[10];
  float* out = (float*)d_out;

  hipLaunchKernelGGL(prep, dim3((376832 + 255) / 256), dim3(256), 0, stream,
                     W1, W2, Wih, Whh);
  hipLaunchKernelGGL(odegru_kernel, dim3(NBLK), dim3(NTHR), 0, stream,
                     x, times, mask, b1, b2, bih, bhh, out);
}